// Round 1
// baseline (68.146 us; speedup 1.0000x reference)
//
#include <hip/hip_runtime.h>
#include <hip/hip_bf16.h>
#include <math.h>

#define BB 8
#define SS 512
#define DD 256
#define PP (SS * (SS - 1) / 2)   // 130816 pairs per batch
#define TILES_PER_B (32 * 33 / 2) // 528 triangular 16x16 tiles

typedef short bf16x8 __attribute__((ext_vector_type(8)));
typedef float f32x4 __attribute__((ext_vector_type(4)));

// fp32 -> bf16 round-to-nearest-even (inputs are finite gaussians, no NaN path needed)
static __device__ inline unsigned short f2bf(float f) {
    unsigned int u = __float_as_uint(f);
    unsigned int r = u + 0x7fffu + ((u >> 16) & 1u);
    return (unsigned short)(r >> 16);
}

// One wave per row: convert 256 fp32 -> bf16, compute fp32 sum of squares.
__global__ __launch_bounds__(256) void prep_kernel(const float* __restrict__ x,
                                                   unsigned short* __restrict__ xb,
                                                   float* __restrict__ norms) {
    int row  = blockIdx.x * 4 + (threadIdx.x >> 6); // 4096 rows total
    int lane = threadIdx.x & 63;
    const float4* src = reinterpret_cast<const float4*>(x + (size_t)row * DD) + lane;
    float4 v = *src;
    float ss = v.x * v.x + v.y * v.y + v.z * v.z + v.w * v.w;
    ushort4 pk;
    pk.x = f2bf(v.x); pk.y = f2bf(v.y); pk.z = f2bf(v.z); pk.w = f2bf(v.w);
    *reinterpret_cast<ushort4*>(xb + (size_t)row * DD + lane * 4) = pk;
    #pragma unroll
    for (int o = 32; o > 0; o >>= 1) ss += __shfl_down(ss, o);
    if (lane == 0) norms[row] = ss;
}

// One wave per 16x16 tile of the lower-triangular pair matrix.
// Gram via mfma_f32_16x16x32_bf16; epilogue d = sqrt(max(ni+nj-2g, eps)).
__global__ __launch_bounds__(256) void dist_kernel(const unsigned short* __restrict__ xb,
                                                   const float* __restrict__ norms,
                                                   float* __restrict__ out) {
    int w    = blockIdx.x * 4 + (threadIdx.x >> 6); // 0..4223
    int lane = threadIdx.x & 63;
    int b    = w / TILES_PER_B;
    int tidx = w - b * TILES_PER_B;
    // largest ti with ti*(ti+1)/2 <= tidx
    int ti = (int)((sqrtf(8.0f * (float)tidx + 1.0f) - 1.0f) * 0.5f);
    while ((ti + 1) * (ti + 2) / 2 <= tidx) ti++;
    while (ti * (ti + 1) / 2 > tidx) ti--;
    int tj = tidx - ti * (ti + 1) / 2;

    int nidx = lane & 15;  // m for A-rows, n for B-rows (both use lane&15)
    int quad = lane >> 4;  // k-quad for operands; row-quad for C/D

    const unsigned short* arow = xb + ((size_t)(b * SS + ti * 16 + nidx)) * DD + quad * 8;
    const unsigned short* brow = xb + ((size_t)(b * SS + tj * 16 + nidx)) * DD + quad * 8;

    f32x4 acc = {0.f, 0.f, 0.f, 0.f};
    #pragma unroll
    for (int k = 0; k < DD; k += 32) {
        bf16x8 av = *reinterpret_cast<const bf16x8*>(arow + k);
        bf16x8 bv = *reinterpret_cast<const bf16x8*>(brow + k);
        acc = __builtin_amdgcn_mfma_f32_16x16x32_bf16(av, bv, acc, 0, 0, 0);
    }

    // C/D layout (m89-verified): col = lane&15 -> j index, row = quad*4+reg -> i index
    int jg = tj * 16 + nidx;
    float nj = norms[b * SS + jg];
    float* outb = out + (size_t)b * PP;
    #pragma unroll
    for (int r = 0; r < 4; r++) {
        int ig = ti * 16 + quad * 4 + r;
        if (ig > jg) {
            float ni = norms[b * SS + ig];
            float d2 = ni + nj - 2.0f * acc[r];
            d2 = fmaxf(d2, 1e-7f);
            outb[(size_t)(ig * (ig - 1) / 2) + jg] = sqrtf(d2);
        }
    }
}

extern "C" void kernel_launch(void* const* d_in, const int* in_sizes, int n_in,
                              void* d_out, int out_size, void* d_ws, size_t ws_size,
                              hipStream_t stream) {
    const float* x = (const float*)d_in[0];
    float* out = (float*)d_out;
    unsigned short* xb = (unsigned short*)d_ws;                      // 2 MB bf16 copy
    float* norms = (float*)((char*)d_ws + (size_t)BB * SS * DD * 2); // 16 KB norms

    prep_kernel<<<1024, 256, 0, stream>>>(x, xb, norms);
    dist_kernel<<<1056, 256, 0, stream>>>(xb, norms, out);
}